// Round 19
// baseline (60.566 us; speedup 1.0000x reference)
//
#include <hip/hip_runtime.h>
#include <hip/hip_bf16.h>

// ROUND 19: spread latency-bound tail kernels over more blocks.
// k5 -> k5a (slot×quarter GEMV1 partials, ~560 blocks) + k5b (reduce+GEMV2).
// k6 -> 1024-thr 4-way-split decoder (r6-verified tail). Scans = r15 exact.

#define NN 20000
#define EE 320000
#define E4 (EE/4)
#define KK 4
#define FIN 512
#define FHID 256
#define FOUT 128
#define FHD 256
#define NH (2*FOUT+3)   // 259
#define CAP1 1024
#define MS2 128
#define BCAP 256
#define BMW 640

__device__ __forceinline__ float dinvf(int indeg) {
  // reference deg includes the self-loop -> always >= 1
  return rsqrtf((float)(indeg + 1));
}

__global__ __launch_bounds__(256) void kz_zero(int4* __restrict__ p, int n4) {
  int i = blockIdx.x * 256 + threadIdx.x;
  if (i < n4) p[i] = make_int4(0, 0, 0, 0);
}

// K12: scan dst planes; collect L1 edges, CAS-claim slot nodes, set slot bitmap.
__global__ __launch_bounds__(256) void k12_scan_claim(const int* __restrict__ ei,
                                                      const int* __restrict__ idx,
                                                      int* __restrict__ cnt1,
                                                      int* __restrict__ L1src,
                                                      int* __restrict__ L1sel,
                                                      int* __restrict__ reg,
                                                      int* __restrict__ slotNode,
                                                      int* __restrict__ mslots,
                                                      unsigned* __restrict__ bA) {
  int k = blockIdx.y;
  int* rk = reg + (size_t)k * NN;
  unsigned* bAk = bA + k * BMW;
  int t0 = idx[2 * k], t1 = idx[2 * k + 1];
  if (blockIdx.x == 0 && threadIdx.x < 2) {
    int node = (threadIdx.x == 0) ? t0 : t1;
    if (atomicCAS(&rk[node], 0, -2) == 0) {
      int s = atomicAdd(&mslots[k], 1);
      if (s < MS2) {
        slotNode[k * MS2 + s] = node; rk[node] = s + 1;
        atomicOr(&bAk[node >> 5], 1u << (node & 31));
      }
    }
  }
  int e4 = blockIdx.x * blockDim.x + threadIdx.x;
  if (e4 >= E4) return;
  const int* srcp = ei + (size_t)k * 2 * EE;
  int4 d4 = ((const int4*)(srcp + EE))[e4];
  int ds[4] = {d4.x, d4.y, d4.z, d4.w};
  #pragma unroll
  for (int c = 0; c < 4; c++) {
    bool h0 = (ds[c] == t0), h1 = (ds[c] == t1);
    if (h0 || h1) {
      int u = srcp[e4 * 4 + c];
      if (h0) {
        int p = atomicAdd(&cnt1[k], 1);
        if (p < CAP1) { L1src[k * CAP1 + p] = u; L1sel[k * CAP1 + p] = 0; }
      }
      if (h1) {
        int p = atomicAdd(&cnt1[k], 1);
        if (p < CAP1) { L1src[k * CAP1 + p] = u; L1sel[k * CAP1 + p] = 1; }
      }
      if (atomicCAS(&rk[u], 0, -2) == 0) {
        int s = atomicAdd(&mslots[k], 1);
        if (s < MS2) {
          slotNode[k * MS2 + s] = u; rk[u] = s + 1;
          atomicOr(&bAk[u >> 5], 1u << (u & 31));
        }
      }
    }
  }
}

// K3: scan with LDS slot-bitmap membership test; bucket append + bB mark.
__global__ __launch_bounds__(256) void k3_scanL2(const int* __restrict__ ei,
                                                 const int* __restrict__ reg,
                                                 const unsigned* __restrict__ bA,
                                                 unsigned* __restrict__ bB,
                                                 int* __restrict__ bcnt,
                                                 int* __restrict__ bucket) {
  __shared__ unsigned lbA[BMW];   // 2.5 KB
  int k = blockIdx.y;
  const unsigned* bAk = bA + k * BMW;
  for (int i = threadIdx.x; i < BMW; i += 256) lbA[i] = bAk[i];
  __syncthreads();
  int e4 = blockIdx.x * blockDim.x + threadIdx.x;
  if (e4 >= E4) return;
  const int* srcp = ei + (size_t)k * 2 * EE;
  int4 d4 = ((const int4*)(srcp + EE))[e4];
  const int* rk = reg + (size_t)k * NN;
  unsigned* bBk = bB + k * BMW;
  int ds[4] = {d4.x, d4.y, d4.z, d4.w};
  #pragma unroll
  for (int c = 0; c < 4; c++) {
    int d = ds[c];
    if ((lbA[d >> 5] >> (d & 31)) & 1u) {
      int s = rk[d] - 1;
      int u = srcp[e4 * 4 + c];
      int p = atomicAdd(&bcnt[k * MS2 + s], 1);
      if (p < BCAP) bucket[((size_t)k * MS2 + s) * BCAP + p] = u;
      atomicOr(&bBk[u >> 5], 1u << (u & 31));
    }
  }
}

// K4: scan with LDS deg-needed-bitmap test; sparse atomicAdd for hits only.
__global__ __launch_bounds__(256) void k4_deg(const int* __restrict__ ei,
                                              const unsigned* __restrict__ bB,
                                              int* __restrict__ deg) {
  __shared__ unsigned lbB[BMW];
  int k = blockIdx.y;
  const unsigned* bBk = bB + k * BMW;
  for (int i = threadIdx.x; i < BMW; i += 256) lbB[i] = bBk[i];
  __syncthreads();
  int e4 = blockIdx.x * blockDim.x + threadIdx.x;
  if (e4 >= E4) return;
  const int4* dst4 = (const int4*)(ei + (size_t)k * 2 * EE + EE);
  int4 d4 = dst4[e4];
  int ds[4] = {d4.x, d4.y, d4.z, d4.w};
  #pragma unroll
  for (int c = 0; c < 4; c++) {
    int d = ds[c];
    if ((lbB[d >> 5] >> (d & 31)) & 1u) atomicAdd(&deg[k * NN + d], 1);
  }
}

// K5A: one block per (slot, quarter): gather the 128-float agg slice, then
// GEMV1 partial over W1 rows [q*128, q*128+128) -> partQ[k][s][q][256].
__global__ __launch_bounds__(256) void k5a_gemv1(const int* __restrict__ slotNode,
                                                 const int* __restrict__ mslots,
                                                 const int* __restrict__ bcnt,
                                                 const int* __restrict__ bucket,
                                                 const int* __restrict__ deg,
                                                 const float* __restrict__ x,
                                                 const float* __restrict__ W1,
                                                 float* __restrict__ partQ) {
  __shared__ int   uS[BCAP];
  __shared__ float duS[BCAP];
  __shared__ float aggq[128];
  __shared__ float gtmp[128];
  int k = blockIdx.y;
  int s = blockIdx.x >> 2, q = blockIdx.x & 3;
  if (s >= mslots[k]) return;
  int tid = threadIdx.x;
  int node = slotNode[k * MS2 + s];
  int rawbc = bcnt[k * MS2 + s];
  int nb = min(rawbc, BCAP);
  const int* bk = bucket + ((size_t)k * MS2 + s) * BCAP;
  if (tid < nb) {
    int u = bk[tid];
    uS[tid] = u;
    duS[tid] = dinvf(deg[k * NN + u]);
  }
  __syncthreads();
  float dn = dinvf(rawbc);   // slot in-degree == bucket count (validated r13+)
  int f = tid & 127, g = tid >> 7;
  const float* xq = x + q * 128 + f;
  float a = (g == 0) ? dn * xq[(size_t)node * FIN] : 0.f;
  for (int e = g; e < nb; e += 2) a += duS[e] * xq[(size_t)uS[e] * FIN];
  if (g == 1) gtmp[f] = a;
  __syncthreads();
  if (g == 0) aggq[f] = dn * (a + gtmp[f]);
  __syncthreads();
  float acc = 0.f;
  const float* w1p = W1 + (size_t)(q * 128) * FHID + tid;
  #pragma unroll 8
  for (int kk = 0; kk < 128; kk++) acc += aggq[kk] * w1p[(size_t)kk * FHID];
  partQ[(((size_t)k * MS2 + s) * 4 + q) * FHID + tid] = acc;
}

// K5B: per slot: hrow = relu(sum_q partQ + b1); GEMV2 -> HW2.
__global__ __launch_bounds__(256) void k5b_gemv2(const int* __restrict__ mslots,
                                                 const float* __restrict__ partQ,
                                                 const float* __restrict__ b1,
                                                 const float* __restrict__ W2,
                                                 float* __restrict__ HW2) {
  __shared__ float hrow[FHID];
  __shared__ float pr[FHID];
  int k = blockIdx.y, s = blockIdx.x;
  if (s >= mslots[k]) return;
  int tid = threadIdx.x;
  const float* pq = partQ + (((size_t)k * MS2 + s) * 4) * FHID;
  {
    float v = pq[tid] + pq[FHID + tid] + pq[2 * FHID + tid] + pq[3 * FHID + tid] + b1[tid];
    hrow[tid] = v > 0.f ? v : 0.f;
  }
  __syncthreads();
  int half = tid >> 7, j = tid & 127;
  float a = 0.f;
  const float* w2p = W2 + (size_t)(half * 128) * FOUT + j;
  #pragma unroll 8
  for (int kk = 0; kk < 128; kk++) a += hrow[half * 128 + kk] * w2p[(size_t)kk * FOUT];
  pr[tid] = a;
  __syncthreads();
  if (half == 0) HW2[((size_t)k * MS2 + s) * FOUT + j] = pr[j] + pr[128 + j];
}

// K6: 1024-thr decoder (r6-verified tail; slot degrees from bcnt).
__global__ __launch_bounds__(1024) void k6_decode(const float* __restrict__ HW2,
                                                  const float* __restrict__ b2,
                                                  const int* __restrict__ cnt1,
                                                  const int* __restrict__ L1src,
                                                  const int* __restrict__ L1sel,
                                                  const int* __restrict__ idx,
                                                  const int* __restrict__ reg,
                                                  const int* __restrict__ bcnt,
                                                  const float* __restrict__ value,
                                                  const float* __restrict__ Wd,
                                                  const float* __restrict__ bd,
                                                  const float* __restrict__ Wp,
                                                  const float* __restrict__ bp,
                                                  float* __restrict__ out) {
  __shared__ float hD[NH + 1];
  __shared__ float oD[FHD];
  __shared__ float pd[4][FHD];
  __shared__ float red[4];
  int k = blockIdx.x;
  int tid = threadIdx.x;
  const int* rk = reg + (size_t)k * NN;
  int n1 = min(cnt1[k], CAP1);
  if (tid < 256) {
    int tsel = tid >> 7, j = tid & 127;
    int t = idx[2 * k + tsel];
    int tslot = rk[t] - 1;
    float dit = dinvf(bcnt[k * MS2 + tslot]);
    float acc = b2[j] + dit * dit * HW2[((size_t)k * MS2 + tslot) * FOUT + j];
    for (int i = 0; i < n1; i++) {
      if (L1sel[k * CAP1 + i] == tsel) {
        int sn = L1src[k * CAP1 + i];
        int ss = rk[sn] - 1;
        float dis = dinvf(bcnt[k * MS2 + ss]);
        acc += dis * dit * HW2[((size_t)k * MS2 + ss) * FOUT + j];
      }
    }
    hD[tsel * FOUT + j] = acc;
    if (tid < 3) hD[2 * FOUT + tid] = value[k * 3 + tid];
  }
  __syncthreads();
  {
    int jj = tid & 255, qd = tid >> 8;
    int i0 = qd * 65, i1 = min(NH, i0 + 65);
    float a2 = (qd == 0) ? bd[jj] : 0.f;
    for (int i = i0; i < i1; i++) a2 += hD[i] * Wd[(size_t)i * FHD + jj];
    pd[qd][jj] = a2;
  }
  __syncthreads();
  if (tid < FHD) {
    float v = pd[0][tid] + pd[1][tid] + pd[2][tid] + pd[3][tid];
    oD[tid] = v > 0.f ? v : 0.f;
  }
  __syncthreads();
  if (tid < FHD) {
    float r = oD[tid] * Wp[tid];
    for (int o2 = 32; o2 > 0; o2 >>= 1) r += __shfl_down(r, o2);
    if ((tid & 63) == 0) red[tid >> 6] = r;
  }
  __syncthreads();
  if (tid == 0) {
    float ssum = red[0] + red[1] + red[2] + red[3] + bp[0];
    out[k] = 1.f / (1.f + expf(-ssum));
  }
}

extern "C" void kernel_launch(void* const* d_in, const int* in_sizes, int n_in,
                              void* d_out, int out_size, void* d_ws, size_t ws_size,
                              hipStream_t stream) {
  const float* x     = (const float*)d_in[0];
  const int*   ei    = (const int*)d_in[1];
  const float* value = (const float*)d_in[2];
  const int*   idx   = (const int*)d_in[3];
  const float* W1    = (const float*)d_in[4];
  const float* b1    = (const float*)d_in[5];
  const float* W2    = (const float*)d_in[6];
  const float* b2    = (const float*)d_in[7];
  const float* Wd    = (const float*)d_in[8];
  const float* bd    = (const float*)d_in[9];
  const float* Wp    = (const float*)d_in[10];
  const float* bp    = (const float*)d_in[11];
  float* out = (float*)d_out;

  char* ws = (char*)d_ws;
  size_t off = 0;
  auto alloc = [&](size_t bytes) -> void* {
    void* p = ws + off;
    off = (off + bytes + 255) & ~(size_t)255;
    return p;
  };
  // --- zeroed region (one kz_zero): reg, deg, bA, bB, bcnt, cnt1, mslots ---
  size_t zints = (size_t)(2 * KK * NN + 2 * KK * BMW + KK * MS2 + 2 * KK);
  int* reg   = (int*)alloc(zints * sizeof(int));
  int* deg   = reg + KK * NN;
  unsigned* bA = (unsigned*)(deg + KK * NN);
  unsigned* bB = bA + KK * BMW;
  int* bcnt  = (int*)(bB + KK * BMW);
  int* cnt1  = bcnt + KK * MS2;
  int* mslots = cnt1 + KK;
  size_t zbytes = zints * sizeof(int);
  // --- non-zeroed scratch ---
  int* L1src = (int*)alloc((size_t)KK * CAP1 * sizeof(int));
  int* L1sel = (int*)alloc((size_t)KK * CAP1 * sizeof(int));
  int* slotNode = (int*)alloc((size_t)KK * MS2 * sizeof(int));
  int* bucket = (int*)alloc((size_t)KK * MS2 * BCAP * sizeof(int));
  float* HW2 = (float*)alloc((size_t)KK * MS2 * FOUT * sizeof(float));
  float* partQ = (float*)alloc((size_t)KK * MS2 * 4 * FHID * sizeof(float));  // 2 MB
  (void)ws_size; (void)in_sizes; (void)n_in; (void)out_size;

  int n4 = (int)((zbytes + 15) / 16);
  dim3 escan((E4 + 255) / 256, KK);

  kz_zero<<<(n4 + 255) / 256, 256, 0, stream>>>((int4*)reg, n4);
  k12_scan_claim<<<escan, 256, 0, stream>>>(ei, idx, cnt1, L1src, L1sel,
                                            reg, slotNode, mslots, bA);
  k3_scanL2<<<escan, 256, 0, stream>>>(ei, reg, bA, bB, bcnt, bucket);
  k4_deg<<<escan, 256, 0, stream>>>(ei, bB, deg);
  k5a_gemv1<<<dim3(MS2 * 4, KK), 256, 0, stream>>>(slotNode, mslots, bcnt, bucket,
                                                   deg, x, W1, partQ);
  k5b_gemv2<<<dim3(MS2, KK), 256, 0, stream>>>(mslots, partQ, b1, W2, HW2);
  k6_decode<<<dim3(KK), 1024, 0, stream>>>(HW2, b2, cnt1, L1src, L1sel, idx, reg,
                                           bcnt, value, Wd, bd, Wp, bp, out);
}